// Round 5
// baseline (737.052 us; speedup 1.0000x reference)
//
#include <hip/hip_runtime.h>
#include <cfloat>

#define DIM_IN 256
#define HIDDEN 32
#define NE 64
#define ECH 16
#define BLOCK 256
#define TPT 2  // tokens per thread

typedef float f32x4 __attribute__((ext_vector_type(4)));  // for nontemporal st

// 2 tokens/thread: every W1/W2 element fetched (scalar pipe, wave-uniform
// index) feeds 2x the FMAs, and the two x streams + rotating prefetch keep
// global loads in flight across the FMA blocks. All register arrays are
// indexed with compile-time constants (full unroll) -> no scratch.
__launch_bounds__(BLOCK, 4)
__global__ void router_fwd(const float* __restrict__ x,
                           const float* __restrict__ W1,
                           const float* __restrict__ b1,
                           const float* __restrict__ W2,
                           const float* __restrict__ b2,
                           float* __restrict__ out, int n) {
  __shared__ float obuf[BLOCK][ECH + 1];  // +1 pad: conflict-free transpose
  const int tid = threadIdx.x;
  const long base = (long)blockIdx.x * (BLOCK * TPT);
  const long t0 = base + tid;
  const long t1 = base + BLOCK + tid;
  const bool av0 = t0 < n, av1 = t1 < n;

  const float4* __restrict__ xr0 =
      reinterpret_cast<const float4*>(x + (av0 ? t0 : 0) * DIM_IN);
  const float4* __restrict__ xr1 =
      reinterpret_cast<const float4*>(x + (av1 ? t1 : 0) * DIM_IN);

  float h0[HIDDEN], h1[HIDDEN];
#pragma unroll
  for (int j = 0; j < HIDDEN; ++j) h0[j] = h1[j] = 0.0f;

  // ---- layer 1: h = x @ W1, 8 rows (32B/token) per iter, prefetch next ----
  float4 c00 = xr0[0], c01 = xr0[1];
  float4 c10 = xr1[0], c11 = xr1[1];

#pragma unroll 1
  for (int i0 = 0; i0 < DIM_IN - 8; i0 += 8) {
    const float4 n00 = xr0[(i0 >> 2) + 2], n01 = xr0[(i0 >> 2) + 3];
    const float4 n10 = xr1[(i0 >> 2) + 2], n11 = xr1[(i0 >> 2) + 3];
    const float xs0[8] = {c00.x, c00.y, c00.z, c00.w, c01.x, c01.y, c01.z, c01.w};
    const float xs1[8] = {c10.x, c10.y, c10.z, c10.w, c11.x, c11.y, c11.z, c11.w};
#pragma unroll
    for (int k = 0; k < 8; ++k) {
      const float* __restrict__ wrow = W1 + (i0 + k) * HIDDEN;  // uniform -> s_load
#pragma unroll
      for (int j = 0; j < HIDDEN; ++j) {
        const float w = wrow[j];
        h0[j] = fmaf(xs0[k], w, h0[j]);
        h1[j] = fmaf(xs1[k], w, h1[j]);
      }
    }
    c00 = n00; c01 = n01; c10 = n10; c11 = n11;
  }
  {  // last 8 rows (no prefetch)
    const int i0 = DIM_IN - 8;
    const float xs0[8] = {c00.x, c00.y, c00.z, c00.w, c01.x, c01.y, c01.z, c01.w};
    const float xs1[8] = {c10.x, c10.y, c10.z, c10.w, c11.x, c11.y, c11.z, c11.w};
#pragma unroll
    for (int k = 0; k < 8; ++k) {
      const float* __restrict__ wrow = W1 + (i0 + k) * HIDDEN;
#pragma unroll
      for (int j = 0; j < HIDDEN; ++j) {
        const float w = wrow[j];
        h0[j] = fmaf(xs0[k], w, h0[j]);
        h1[j] = fmaf(xs1[k], w, h1[j]);
      }
    }
  }

  // bias + tanh.  tanh(v) = 1 - 2/(e^{2v}+1): no inf/inf NaN.
#pragma unroll
  for (int j = 0; j < HIDDEN; ++j) {
    const float bj = b1[j];
    const float e0 = __expf(2.0f * (h0[j] + bj));
    const float e1 = __expf(2.0f * (h1[j] + bj));
    h0[j] = 1.0f - 2.0f / (e0 + 1.0f);
    h1[j] = 1.0f - 2.0f / (e1 + 1.0f);
  }

  // ---- layer 2 in 16-expert chunks, both tokens per W2 fetch ----
  float v1a = -FLT_MAX, v2a = -FLT_MAX, Sa = 0.0f;
  float v1b = -FLT_MAX, v2b = -FLT_MAX, Sb = 0.0f;
  int i1a = 0, i2a = 0, i1b = 0, i2b = 0;

#pragma unroll 1
  for (int c = 0; c < NE / ECH; ++c) {
    float z0[ECH], z1[ECH];
#pragma unroll
    for (int e = 0; e < ECH; ++e) z0[e] = z1[e] = 0.0f;
#pragma unroll
    for (int j = 0; j < HIDDEN; ++j) {
      const float* __restrict__ wrow = W2 + j * NE + c * ECH;  // uniform
      const float ha = h0[j], hb = h1[j];
#pragma unroll
      for (int e = 0; e < ECH; ++e) {
        const float w = wrow[e];
        z0[e] = fmaf(ha, w, z0[e]);
        z1[e] = fmaf(hb, w, z1[e]);
      }
    }
    const float ma = v1a, mb = v1b;
    // strict '>' ascending scan => ties pick lower index (lax.top_k)
#pragma unroll
    for (int e = 0; e < ECH; ++e) {
      const float bz = b2[c * ECH + e];
      const int ge = c * ECH + e;
      const float va = (z0[e] + bz) * 10.0f;  // /TEMP
      z0[e] = va;
      bool g1 = va > v1a, g2 = va > v2a;
      v2a = g1 ? v1a : (g2 ? va : v2a);
      i2a = g1 ? i1a : (g2 ? ge : i2a);
      v1a = g1 ? va : v1a;
      i1a = g1 ? ge : i1a;
      const float vb = (z1[e] + bz) * 10.0f;
      z1[e] = vb;
      g1 = vb > v1b; g2 = vb > v2b;
      v2b = g1 ? v1b : (g2 ? vb : v2b);
      i2b = g1 ? i1b : (g2 ? ge : i2b);
      v1b = g1 ? vb : v1b;
      i1b = g1 ? ge : i1b;
    }
    Sa *= __expf(ma - v1a);  // rescale old sums to new max (chunk 0: 0*0=0)
    Sb *= __expf(mb - v1b);
#pragma unroll
    for (int e = 0; e < ECH; ++e) {
      Sa += __expf(z0[e] - v1a);
      Sb += __expf(z1[e] - v1b);
    }
  }

  const float paA = 1.0f / Sa, pbA = __expf(v2a - v1a) / Sa;
  const float dA = paA + pbA + 1e-9f;  // ref renorm formula
  const float oaA = av0 ? paA / dA : 0.0f;
  const float obA = av0 ? pbA / dA : 0.0f;
  const float paB = 1.0f / Sb, pbB = __expf(v2b - v1b) / Sb;
  const float dB = paB + pbB + 1e-9f;
  const float oaB = av1 ? paB / dB : 0.0f;
  const float obB = av1 ? pbB / dB : 0.0f;

  // ---- output: LDS transpose -> full 64B-line nontemporal stores ----
#pragma unroll 1
  for (int s = 0; s < TPT; ++s) {
    const float oa = s == 0 ? oaA : oaB;
    const float ob = s == 0 ? obA : obB;
    const int i1 = s == 0 ? i1a : i1b;
    const int i2 = s == 0 ? i2a : i2b;
    const long sbase = base + (long)s * BLOCK;
#pragma unroll 1
    for (int c = 0; c < NE / ECH; ++c) {
      __syncthreads();  // previous round's readers done before overwrite
#pragma unroll
      for (int e = 0; e < ECH; ++e) {
        const int ge = c * ECH + e;
        obuf[tid][e] = (ge == i1) ? oa : ((ge == i2) ? ob : 0.0f);
      }
      __syncthreads();
#pragma unroll
      for (int m = 0; m < 4; ++m) {
        const int f = m * BLOCK + tid;  // consecutive lanes -> consecutive 16B
        const int tok = f >> 2, part = f & 3;
        if (sbase + tok < n) {
          f32x4 v;
          v.x = obuf[tok][part * 4 + 0];
          v.y = obuf[tok][part * 4 + 1];
          v.z = obuf[tok][part * 4 + 2];
          v.w = obuf[tok][part * 4 + 3];
          f32x4* dst = reinterpret_cast<f32x4*>(
              out + (sbase + tok) * (long)NE + c * ECH) + part;
          __builtin_nontemporal_store(v, dst);
        }
      }
    }
  }
}

extern "C" void kernel_launch(void* const* d_in, const int* in_sizes, int n_in,
                              void* d_out, int out_size, void* d_ws, size_t ws_size,
                              hipStream_t stream) {
  const float* x  = (const float*)d_in[0];
  const float* W1 = (const float*)d_in[1];
  const float* b1 = (const float*)d_in[2];
  const float* W2 = (const float*)d_in[3];
  const float* b2 = (const float*)d_in[4];
  float* out = (float*)d_out;
  const int n_tokens = in_sizes[0] / DIM_IN;
  const int tokens_per_block = BLOCK * TPT;
  const int grid = (n_tokens + tokens_per_block - 1) / tokens_per_block;
  hipLaunchKernelGGL(router_fwd, dim3(grid), dim3(BLOCK), 0, stream,
                     x, W1, b1, W2, b2, out, n_tokens);
}